// Round 15
// baseline (93.132 us; speedup 1.0000x reference)
//
#include <hip/hip_runtime.h>

#define DIM 64
#define TILE_B 9
#define TILE (1 << TILE_B)     // 512 nodes per tile
#define CAPT 8192              // edge slots per tile (mean ~5100 + padding)
#define CHUNK 1024             // edges per partition block
#define TB_PART 128            // partition block size
#define MAXNT 512              // max tiles supported by LDS arrays

typedef unsigned int u32x4 __attribute__((ext_vector_type(4)));

// zero gcur_d + gcur_s (2*MAXNT = 1024 ints) in one block
__global__ void zero_init_kernel(int* __restrict__ g) {
    g[threadIdx.x] = 0;
}

// ---------- Phase 1: tile partition (src-side and dst-side) ----------
__global__ void partition_kernel(const int* __restrict__ src, const int* __restrict__ dst,
                                 int* __restrict__ gcur_d, int* __restrict__ gcur_s,
                                 unsigned int* __restrict__ ebuf,
                                 unsigned short* __restrict__ sbuf,
                                 int n_edges, int nt) {
    __shared__ int cnt_d[MAXNT];
    __shared__ int cnt_s[MAXNT];
    const int tid = threadIdx.x;
    for (int k = tid; k < nt; k += TB_PART) { cnt_d[k] = 0; cnt_s[k] = 0; }
    __syncthreads();

    const int base = blockIdx.x * CHUNK;
    const int rem = min(CHUNK, n_edges - base);
    const int rem4 = rem >> 2;
    const int4* src4 = reinterpret_cast<const int4*>(src + base);
    const int4* dst4 = reinterpret_cast<const int4*>(dst + base);

    int4 sv[2], dv[2];
    bool ok[2];
    #pragma unroll
    for (int k = 0; k < 2; ++k) {
        int i4 = tid + k * TB_PART;
        ok[k] = (i4 < rem4);
        if (ok[k]) { sv[k] = src4[i4]; dv[k] = dst4[i4]; }
    }
    #pragma unroll
    for (int k = 0; k < 2; ++k) {
        if (ok[k]) {
            atomicAdd(&cnt_d[dv[k].x >> TILE_B], 1); atomicAdd(&cnt_s[sv[k].x >> TILE_B], 1);
            atomicAdd(&cnt_d[dv[k].y >> TILE_B], 1); atomicAdd(&cnt_s[sv[k].y >> TILE_B], 1);
            atomicAdd(&cnt_d[dv[k].z >> TILE_B], 1); atomicAdd(&cnt_s[sv[k].z >> TILE_B], 1);
            atomicAdd(&cnt_d[dv[k].w >> TILE_B], 1); atomicAdd(&cnt_s[sv[k].w >> TILE_B], 1);
        }
    }
    if (tid == 0) {
        for (int j = rem & ~3; j < rem; ++j) {
            atomicAdd(&cnt_d[dst[base + j] >> TILE_B], 1);
            atomicAdd(&cnt_s[src[base + j] >> TILE_B], 1);
        }
    }
    __syncthreads();
    for (int k = tid; k < nt; k += TB_PART) {
        int cd = cnt_d[k];
        if (cd) cnt_d[k] = atomicAdd(&gcur_d[k], cd);
        int cs = cnt_s[k];
        if (cs) cnt_s[k] = atomicAdd(&gcur_s[k], cs);
    }
    __syncthreads();
    #pragma unroll
    for (int k = 0; k < 2; ++k) {
        if (ok[k]) {
            int ss[4] = {sv[k].x, sv[k].y, sv[k].z, sv[k].w};
            int dd[4] = {dv[k].x, dv[k].y, dv[k].z, dv[k].w};
            #pragma unroll
            for (int q = 0; q < 4; ++q) {
                int s = ss[q], d = dd[q];
                int td = d >> TILE_B;
                int p = atomicAdd(&cnt_d[td], 1);
                if (p < CAPT)
                    ebuf[(size_t)td * CAPT + p] =
                        ((unsigned int)(d & (TILE - 1)) << 23) | (unsigned int)s;
                int ts = s >> TILE_B;
                int p2 = atomicAdd(&cnt_s[ts], 1);
                if (p2 < CAPT)
                    sbuf[(size_t)ts * CAPT + p2] = (unsigned short)(s & (TILE - 1));
            }
        }
    }
    if (tid == 0) {
        for (int j = rem & ~3; j < rem; ++j) {
            int s = src[base + j], d = dst[base + j];
            int td = d >> TILE_B;
            int p = atomicAdd(&cnt_d[td], 1);
            if (p < CAPT)
                ebuf[(size_t)td * CAPT + p] =
                    ((unsigned int)(d & (TILE - 1)) << 23) | (unsigned int)s;
            int ts = s >> TILE_B;
            int p2 = atomicAdd(&cnt_s[ts], 1);
            if (p2 < CAPT)
                sbuf[(size_t)ts * CAPT + p2] = (unsigned short)(s & (TILE - 1));
        }
    }
}

// ---------- Phase 2 (fused): blocks [0,nt) CSR per dst-tile;
//            blocks [nt,2nt) src histogram -> sq + bf16 table scale ----------
// nodeinfo[n] = { meta: offset(13b)<<13 | count(13b),  sq_bits: f32 }
__global__ void tile_build_kernel(const unsigned int* __restrict__ ebuf,
                                  const unsigned short* __restrict__ sbuf,
                                  const int* __restrict__ gcur_d,
                                  const int* __restrict__ gcur_s,
                                  const float* __restrict__ embed,
                                  int* __restrict__ sorted_src,
                                  uint2* __restrict__ nodeinfo,
                                  unsigned short* __restrict__ table,
                                  int n_nodes, int nt) {
    __shared__ unsigned int h[TILE];
    __shared__ int off[TILE];
    __shared__ int stmp[256];
    __shared__ float hsq[TILE];
    const int tid = threadIdx.x;

    if (blockIdx.x >= nt) {
        // ---- sq + table-scale role ----
        const int t = blockIdx.x - nt;
        if (t == 0 && tid < 32)   // zero the sentinel row table[n_nodes]
            reinterpret_cast<unsigned int*>(table + (size_t)n_nodes * DIM)[tid] = 0u;
        for (int k = tid; k < TILE; k += blockDim.x) h[k] = 0u;
        __syncthreads();
        const int ne = min(gcur_s[t], CAPT);
        const unsigned short* p = sbuf + (size_t)t * CAPT;
        const unsigned int* p2 = reinterpret_cast<const unsigned int*>(p);
        const int ne2 = ne >> 1;
        for (int j = tid; j < ne2; j += blockDim.x) {
            unsigned int v = p2[j];
            atomicAdd(&h[v & 0xffffu], 1u);
            atomicAdd(&h[v >> 16], 1u);
        }
        if (tid == 0 && (ne & 1)) atomicAdd(&h[p[ne - 1]], 1u);
        __syncthreads();
        const int base = t << TILE_B;
        for (int k = tid; k < TILE; k += blockDim.x) {
            int node = base + k;
            float s = rsqrtf((float)h[k]);
            hsq[k] = s;
            if (node < n_nodes) nodeinfo[node].y = __float_as_uint(s);
        }
        __syncthreads();
        const int rows = min(TILE, n_nodes - base);
        for (int u = tid; u < rows * 8; u += blockDim.x) {
            int row = u >> 3;
            int ch = u & 7;
            float s = hsq[row];
            const float4* pe =
                reinterpret_cast<const float4*>(embed + (size_t)(base + row) * DIM + ch * 8);
            float4 v0 = pe[0], v1 = pe[1];
            float vals[8] = {v0.x, v0.y, v0.z, v0.w, v1.x, v1.y, v1.z, v1.w};
            unsigned int w[4];
            #pragma unroll
            for (int k2 = 0; k2 < 4; ++k2) {
                unsigned int lo = __float_as_uint(vals[2 * k2] * s);
                unsigned int hi = __float_as_uint(vals[2 * k2 + 1] * s);
                lo += 0x7fffu + ((lo >> 16) & 1u);
                hi += 0x7fffu + ((hi >> 16) & 1u);
                w[k2] = (lo >> 16) | (hi & 0xffff0000u);
            }
            uint4 o = {w[0], w[1], w[2], w[3]};
            reinterpret_cast<uint4*>(table + (size_t)(base + row) * DIM + ch * 8)[0] = o;
        }
        return;
    }

    // ---- CSR role (even-padded segments, sentinel-filled holes) ----
    const int t = blockIdx.x;
    for (int k = tid; k < TILE; k += blockDim.x) h[k] = 0u;
    __syncthreads();
    const int ne = min(gcur_d[t], CAPT);
    const unsigned int* p = ebuf + (size_t)t * CAPT;
    const uint2* p2 = reinterpret_cast<const uint2*>(p);
    const int ne2 = ne >> 1;
    for (int j = tid; j < ne2; j += blockDim.x) {
        uint2 e2 = p2[j];
        atomicAdd(&h[e2.x >> 23], 1u);
        atomicAdd(&h[e2.y >> 23], 1u);
    }
    if (tid == 0 && (ne & 1)) atomicAdd(&h[p[ne - 1] >> 23], 1u);
    __syncthreads();
    int v0 = (int)h[2 * tid];
    int v1 = (int)h[2 * tid + 1];
    int v0p = (v0 + 1) & ~1;
    int v1p = (v1 + 1) & ~1;
    int pair = v0p + v1p;
    stmp[tid] = pair;
    __syncthreads();
    for (int o = 1; o < 256; o <<= 1) {
        int x = (tid >= o) ? stmp[tid - o] : 0;
        __syncthreads();
        stmp[tid] += x;
        __syncthreads();
    }
    int excl = stmp[tid] - pair;             // even
    off[2 * tid] = excl;
    off[2 * tid + 1] = excl + v0p;
    const int base = t << TILE_B;
    {
        int n0 = base + 2 * tid;
        if (n0 < n_nodes)
            nodeinfo[n0].x = ((unsigned int)min(excl, CAPT - 1) << 13) |
                             (unsigned int)min(v0, CAPT - 1);
        int n1 = n0 + 1;
        if (n1 < n_nodes)
            nodeinfo[n1].x = ((unsigned int)min(excl + v0p, CAPT - 1) << 13) |
                             (unsigned int)min(v1, CAPT - 1);
    }
    __syncthreads();
    for (int k = tid; k < TILE; k += blockDim.x) h[k] = (unsigned int)off[k];
    __syncthreads();
    int* sout = sorted_src + (size_t)t * CAPT;
    for (int j = tid; j < ne2; j += blockDim.x) {
        uint2 e2 = p2[j];
        int dlo = (int)(e2.x >> 23);
        int pos = (int)atomicAdd(&h[dlo], 1u);
        if (pos < CAPT) sout[pos] = (int)(e2.x & 0x7fffffu);
        dlo = (int)(e2.y >> 23);
        pos = (int)atomicAdd(&h[dlo], 1u);
        if (pos < CAPT) sout[pos] = (int)(e2.y & 0x7fffffu);
    }
    if (tid == 0 && (ne & 1)) {
        unsigned int e = p[ne - 1];
        int dlo = (int)(e >> 23);
        int pos = (int)atomicAdd(&h[dlo], 1u);
        if (pos < CAPT) sout[pos] = (int)(e & 0x7fffffu);
    }
    __syncthreads();
    // sentinel-fill odd-count holes: h[k] is now the end cursor (off + count)
    for (int k = tid; k < TILE; k += blockDim.x) {
        int endc = (int)h[k];
        int cnt = endc - off[k];
        if ((cnt & 1) && endc < CAPT)
            sout[endc] = n_nodes;    // zero row
    }
}

// ---------- aggregate: wave per node, CSR, bf16 table, branchless int2 pairs ----------
__global__ void aggregate_csr_kernel(const unsigned short* __restrict__ table,
                                     const int* __restrict__ sorted_src,
                                     const uint2* __restrict__ nodeinfo,
                                     float* __restrict__ out, int n_nodes) {
    int gid = blockIdx.x * blockDim.x + threadIdx.x;
    int node = gid >> 6;
    if (node >= n_nodes) return;
    int lane = threadIdx.x & 63;
    int g = lane >> 3;
    int c = lane & 7;
    uint2 ni = nodeinfo[node];                                // single 8B load
    float sn = __uint_as_float(ni.y);
    int start = ((node >> TILE_B) * CAPT) + (int)(ni.x >> 13);  // even
    int cntp = ((int)(ni.x & 0x1fffu) + 1) & ~1;                // padded to even
    float a0 = 0.f, a1 = 0.f, a2 = 0.f, a3 = 0.f, a4 = 0.f, a5 = 0.f, a6 = 0.f, a7 = 0.f;
    for (int k2 = 2 * g; k2 < cntp; k2 += 16) {
        int2 ss = *reinterpret_cast<const int2*>(sorted_src + start + k2);  // 8B aligned
        u32x4 r1 = *reinterpret_cast<const u32x4*>(table + (size_t)ss.x * DIM + c * 8);
        u32x4 r2 = *reinterpret_cast<const u32x4*>(table + (size_t)ss.y * DIM + c * 8);
        a0 += __uint_as_float(r1.x << 16);         a0 += __uint_as_float(r2.x << 16);
        a1 += __uint_as_float(r1.x & 0xffff0000u); a1 += __uint_as_float(r2.x & 0xffff0000u);
        a2 += __uint_as_float(r1.y << 16);         a2 += __uint_as_float(r2.y << 16);
        a3 += __uint_as_float(r1.y & 0xffff0000u); a3 += __uint_as_float(r2.y & 0xffff0000u);
        a4 += __uint_as_float(r1.z << 16);         a4 += __uint_as_float(r2.z << 16);
        a5 += __uint_as_float(r1.z & 0xffff0000u); a5 += __uint_as_float(r2.z & 0xffff0000u);
        a6 += __uint_as_float(r1.w << 16);         a6 += __uint_as_float(r2.w << 16);
        a7 += __uint_as_float(r1.w & 0xffff0000u); a7 += __uint_as_float(r2.w & 0xffff0000u);
    }
    #pragma unroll
    for (int mm = 8; mm <= 32; mm <<= 1) {
        a0 += __shfl_xor(a0, mm, 64); a1 += __shfl_xor(a1, mm, 64);
        a2 += __shfl_xor(a2, mm, 64); a3 += __shfl_xor(a3, mm, 64);
        a4 += __shfl_xor(a4, mm, 64); a5 += __shfl_xor(a5, mm, 64);
        a6 += __shfl_xor(a6, mm, 64); a7 += __shfl_xor(a7, mm, 64);
    }
    if (g == 0) {
        float* o = out + (size_t)node * DIM + c * 8;
        float4 r0 = {a0 * sn, a1 * sn, a2 * sn, a3 * sn};
        float4 r1 = {a4 * sn, a5 * sn, a6 * sn, a7 * sn};
        *reinterpret_cast<float4*>(o) = r0;
        *reinterpret_cast<float4*>(o + 4) = r1;
    }
}

// ---------- fallback path (tiny ws or huge n_nodes) ----------
__global__ void sdeg_atomic_kernel(const int* __restrict__ src, int* __restrict__ sdeg,
                                   int n_edges) {
    int i = blockIdx.x * blockDim.x + threadIdx.x;
    if (i < n_edges) atomicAdd(&sdeg[src[i]], 1);
}
__global__ void sq_from_sdeg_kernel(const int* __restrict__ sdeg, float* __restrict__ sq, int n) {
    int i = blockIdx.x * blockDim.x + threadIdx.x;
    if (i < n) sq[i] = rsqrtf((float)sdeg[i]);
}
__global__ void build_ll_kernel(const int* __restrict__ src, const int* __restrict__ dst,
                                int* __restrict__ head, int2* __restrict__ list, int n_edges) {
    int i = blockIdx.x * blockDim.x + threadIdx.x;
    if (i >= n_edges) return;
    int s = src[i];
    int d = dst[i];
    int prev = atomicExch(&head[d], i);
    list[i] = make_int2(prev, s);
}
__global__ void aggregate_ll_f32_kernel(const float* __restrict__ embed,
                                        const float* __restrict__ sq,
                                        const int* __restrict__ head,
                                        const int2* __restrict__ list,
                                        float* __restrict__ out, int n_nodes) {
    int gid = blockIdx.x * blockDim.x + threadIdx.x;
    int node = gid >> 3;
    if (node >= n_nodes) return;
    int c = gid & 7;
    int cur = head[node];
    float4 A0 = {0.f, 0.f, 0.f, 0.f}, A1 = {0.f, 0.f, 0.f, 0.f};
    while (cur >= 0) {
        int2 v = list[cur];
        cur = v.x;
        int s = v.y;
        float sc = sq[s];
        const float4* row = reinterpret_cast<const float4*>(embed + (size_t)s * DIM + c * 8);
        float4 v0 = row[0], v1 = row[1];
        A0.x += v0.x * sc; A0.y += v0.y * sc; A0.z += v0.z * sc; A0.w += v0.w * sc;
        A1.x += v1.x * sc; A1.y += v1.y * sc; A1.z += v1.z * sc; A1.w += v1.w * sc;
    }
    float sn = sq[node];
    float4 r0 = {A0.x * sn, A0.y * sn, A0.z * sn, A0.w * sn};
    float4 r1 = {A1.x * sn, A1.y * sn, A1.z * sn, A1.w * sn};
    float4* o = reinterpret_cast<float4*>(out + (size_t)node * DIM + c * 8);
    o[0] = r0; o[1] = r1;
}

static inline size_t align16(size_t x) { return (x + 15) & ~(size_t)15; }

extern "C" void kernel_launch(void* const* d_in, const int* in_sizes, int n_in,
                              void* d_out, int out_size, void* d_ws, size_t ws_size,
                              hipStream_t stream) {
    const float* embed = (const float*)d_in[0];
    const int*   src   = (const int*)d_in[1];
    const int*   dst   = (const int*)d_in[2];
    float*       out   = (float*)d_out;

    const int n_nodes = in_sizes[0] / DIM;
    const int n_edges = in_sizes[1];
    const int nt = (n_nodes + TILE - 1) >> TILE_B;
    const int tb = 256;

    // Regions: gcur_d | gcur_s | nodeinfo uint2[n] | ebuf u32 | table bf16[(n+1)*DIM]
    //          | sbuf u16 | sorted i32
    size_t o_gcur_d = 0;
    size_t o_gcur_s = o_gcur_d + (size_t)MAXNT * 4;
    size_t o_ninfo  = align16(o_gcur_s + (size_t)MAXNT * 4);
    size_t o_ebuf   = align16(o_ninfo + (size_t)n_nodes * 8);
    size_t o_table  = align16(o_ebuf + (size_t)nt * CAPT * 4);
    size_t o_sbuf   = align16(o_table + (size_t)(n_nodes + 1) * DIM * 2);
    size_t o_sorted = align16(o_sbuf + (size_t)nt * CAPT * 2);
    size_t need     = o_sorted + (size_t)nt * CAPT * 4;

    const bool fast = (nt <= MAXNT) && (n_nodes <= (1 << 23)) && (ws_size >= need);

    if (fast) {
        char* ws = (char*)d_ws;
        int* gcur_d = (int*)(ws + o_gcur_d);
        int* gcur_s = (int*)(ws + o_gcur_s);
        uint2* nodeinfo = (uint2*)(ws + o_ninfo);
        unsigned int*   ebuf  = (unsigned int*)(ws + o_ebuf);
        unsigned short* table = (unsigned short*)(ws + o_table);
        unsigned short* sbuf  = (unsigned short*)(ws + o_sbuf);
        int* sorted_src = (int*)(ws + o_sorted);

        zero_init_kernel<<<1, 2 * MAXNT, 0, stream>>>(gcur_d);

        const int g1 = (n_edges + CHUNK - 1) / CHUNK;
        partition_kernel<<<g1, TB_PART, 0, stream>>>(src, dst, gcur_d, gcur_s, ebuf, sbuf,
                                                     n_edges, nt);
        tile_build_kernel<<<2 * nt, tb, 0, stream>>>(ebuf, sbuf, gcur_d, gcur_s, embed,
                                                     sorted_src, nodeinfo, table,
                                                     n_nodes, nt);
        const long long at = (long long)n_nodes * 64;
        aggregate_csr_kernel<<<(int)((at + 127) / 128), 128, 0, stream>>>(
            table, sorted_src, nodeinfo, out, n_nodes);
    } else {
        int*   head = (int*)d_ws;
        float* sq   = (float*)(head + n_nodes);
        int*   sdeg = (int*)(sq + n_nodes);
        int2*  list = (int2*)(sdeg + n_nodes);
        (void)hipMemsetAsync(head, 0xFF, (size_t)n_nodes * 4, stream);
        (void)hipMemsetAsync(sdeg, 0, (size_t)n_nodes * 4, stream);
        sdeg_atomic_kernel<<<(n_edges + tb - 1) / tb, tb, 0, stream>>>(src, sdeg, n_edges);
        sq_from_sdeg_kernel<<<(n_nodes + tb - 1) / tb, tb, 0, stream>>>(sdeg, sq, n_nodes);
        build_ll_kernel<<<(n_edges + tb - 1) / tb, tb, 0, stream>>>(src, dst, head,
                                                                    list, n_edges);
        const int at = n_nodes * 8;
        aggregate_ll_f32_kernel<<<(at + tb - 1) / tb, tb, 0, stream>>>(
            embed, sq, head, list, out, n_nodes);
    }
}

// Round 16
// 75.065 us; speedup vs baseline: 1.2407x; 1.2407x over previous
//
#include <hip/hip_runtime.h>

#define DIM 64
#define TILE_B 9
#define TILE (1 << TILE_B)     // 512 nodes per tile
#define CAPT 8192              // edge slots per tile (mean ~5100 + padding)
#define CHUNK 2048             // edges per partition block
#define MAXNT 512              // max tiles supported by LDS arrays

typedef unsigned int u32x4 __attribute__((ext_vector_type(4)));

// zero gcur_d/gcur_s (blocks 0..3) and the sentinel zero-row table[n_nodes] (block 4)
__global__ void zero_init_kernel(int* __restrict__ g, unsigned int* __restrict__ pad_row) {
    if (blockIdx.x < 4) {
        g[threadIdx.x + blockIdx.x * blockDim.x] = 0;
    } else if (threadIdx.x < 32) {
        pad_row[threadIdx.x] = 0u;      // 32 u32 = 64 bf16 = one table row
    }
}

// ---------- Phase 1: tile partition (src-side and dst-side) ----------
__global__ void partition_kernel(const int* __restrict__ src, const int* __restrict__ dst,
                                 int* __restrict__ gcur_d, int* __restrict__ gcur_s,
                                 unsigned int* __restrict__ ebuf,
                                 unsigned short* __restrict__ sbuf,
                                 int n_edges, int nt) {
    __shared__ int cnt_d[MAXNT];
    __shared__ int cnt_s[MAXNT];
    const int tid = threadIdx.x;
    for (int k = tid; k < nt; k += blockDim.x) { cnt_d[k] = 0; cnt_s[k] = 0; }
    __syncthreads();

    const int base = blockIdx.x * CHUNK;
    const int rem = min(CHUNK, n_edges - base);
    const int rem4 = rem >> 2;
    const int4* src4 = reinterpret_cast<const int4*>(src + base);
    const int4* dst4 = reinterpret_cast<const int4*>(dst + base);

    int4 sv[2], dv[2];
    bool ok[2];
    #pragma unroll
    for (int k = 0; k < 2; ++k) {
        int i4 = tid + k * 256;
        ok[k] = (i4 < rem4);
        if (ok[k]) { sv[k] = src4[i4]; dv[k] = dst4[i4]; }
    }
    #pragma unroll
    for (int k = 0; k < 2; ++k) {
        if (ok[k]) {
            atomicAdd(&cnt_d[dv[k].x >> TILE_B], 1); atomicAdd(&cnt_s[sv[k].x >> TILE_B], 1);
            atomicAdd(&cnt_d[dv[k].y >> TILE_B], 1); atomicAdd(&cnt_s[sv[k].y >> TILE_B], 1);
            atomicAdd(&cnt_d[dv[k].z >> TILE_B], 1); atomicAdd(&cnt_s[sv[k].z >> TILE_B], 1);
            atomicAdd(&cnt_d[dv[k].w >> TILE_B], 1); atomicAdd(&cnt_s[sv[k].w >> TILE_B], 1);
        }
    }
    if (tid == 0) {
        for (int j = rem & ~3; j < rem; ++j) {
            atomicAdd(&cnt_d[dst[base + j] >> TILE_B], 1);
            atomicAdd(&cnt_s[src[base + j] >> TILE_B], 1);
        }
    }
    __syncthreads();
    for (int k = tid; k < nt; k += blockDim.x) {
        int cd = cnt_d[k];
        if (cd) cnt_d[k] = atomicAdd(&gcur_d[k], cd);
        int cs = cnt_s[k];
        if (cs) cnt_s[k] = atomicAdd(&gcur_s[k], cs);
    }
    __syncthreads();
    #pragma unroll
    for (int k = 0; k < 2; ++k) {
        if (ok[k]) {
            int ss[4] = {sv[k].x, sv[k].y, sv[k].z, sv[k].w};
            int dd[4] = {dv[k].x, dv[k].y, dv[k].z, dv[k].w};
            #pragma unroll
            for (int q = 0; q < 4; ++q) {
                int s = ss[q], d = dd[q];
                int td = d >> TILE_B;
                int p = atomicAdd(&cnt_d[td], 1);
                if (p < CAPT)
                    ebuf[(size_t)td * CAPT + p] =
                        ((unsigned int)(d & (TILE - 1)) << 23) | (unsigned int)s;
                int ts = s >> TILE_B;
                int p2 = atomicAdd(&cnt_s[ts], 1);
                if (p2 < CAPT)
                    sbuf[(size_t)ts * CAPT + p2] = (unsigned short)(s & (TILE - 1));
            }
        }
    }
    if (tid == 0) {
        for (int j = rem & ~3; j < rem; ++j) {
            int s = src[base + j], d = dst[base + j];
            int td = d >> TILE_B;
            int p = atomicAdd(&cnt_d[td], 1);
            if (p < CAPT)
                ebuf[(size_t)td * CAPT + p] =
                    ((unsigned int)(d & (TILE - 1)) << 23) | (unsigned int)s;
            int ts = s >> TILE_B;
            int p2 = atomicAdd(&cnt_s[ts], 1);
            if (p2 < CAPT)
                sbuf[(size_t)ts * CAPT + p2] = (unsigned short)(s & (TILE - 1));
        }
    }
}

// ---------- Phase 2 (fused): blocks [0,nt) CSR per dst-tile;
//            blocks [nt,2nt) src histogram -> sq + bf16 table scale ----------
// nodeinfo[n] = { meta: offset(13b)<<13 | count(13b),  sq_bits: f32 }
__global__ void tile_build_kernel(const unsigned int* __restrict__ ebuf,
                                  const unsigned short* __restrict__ sbuf,
                                  const int* __restrict__ gcur_d,
                                  const int* __restrict__ gcur_s,
                                  const float* __restrict__ embed,
                                  int* __restrict__ sorted_src,
                                  uint2* __restrict__ nodeinfo,
                                  unsigned short* __restrict__ table,
                                  int n_nodes, int nt) {
    __shared__ unsigned int h[TILE];
    __shared__ int off[TILE];
    __shared__ int stmp[256];
    __shared__ float hsq[TILE];
    const int tid = threadIdx.x;

    if (blockIdx.x >= nt) {
        // ---- sq + table-scale role ----
        const int t = blockIdx.x - nt;
        for (int k = tid; k < TILE; k += blockDim.x) h[k] = 0u;
        __syncthreads();
        const int ne = min(gcur_s[t], CAPT);
        const unsigned short* p = sbuf + (size_t)t * CAPT;
        const unsigned int* p2 = reinterpret_cast<const unsigned int*>(p);
        const int ne2 = ne >> 1;
        for (int j = tid; j < ne2; j += blockDim.x) {
            unsigned int v = p2[j];
            atomicAdd(&h[v & 0xffffu], 1u);
            atomicAdd(&h[v >> 16], 1u);
        }
        if (tid == 0 && (ne & 1)) atomicAdd(&h[p[ne - 1]], 1u);
        __syncthreads();
        const int base = t << TILE_B;
        for (int k = tid; k < TILE; k += blockDim.x) {
            int node = base + k;
            float s = rsqrtf((float)h[k]);
            hsq[k] = s;
            if (node < n_nodes) nodeinfo[node].y = __float_as_uint(s);
        }
        __syncthreads();
        const int rows = min(TILE, n_nodes - base);
        for (int u = tid; u < rows * 8; u += blockDim.x) {
            int row = u >> 3;
            int ch = u & 7;
            float s = hsq[row];
            const float4* pe =
                reinterpret_cast<const float4*>(embed + (size_t)(base + row) * DIM + ch * 8);
            float4 v0 = pe[0], v1 = pe[1];
            float vals[8] = {v0.x, v0.y, v0.z, v0.w, v1.x, v1.y, v1.z, v1.w};
            unsigned int w[4];
            #pragma unroll
            for (int k2 = 0; k2 < 4; ++k2) {
                unsigned int lo = __float_as_uint(vals[2 * k2] * s);
                unsigned int hi = __float_as_uint(vals[2 * k2 + 1] * s);
                lo += 0x7fffu + ((lo >> 16) & 1u);
                hi += 0x7fffu + ((hi >> 16) & 1u);
                w[k2] = (lo >> 16) | (hi & 0xffff0000u);
            }
            uint4 o = {w[0], w[1], w[2], w[3]};
            reinterpret_cast<uint4*>(table + (size_t)(base + row) * DIM + ch * 8)[0] = o;
        }
        return;
    }

    // ---- CSR role (even-padded segments, sentinel-filled holes) ----
    const int t = blockIdx.x;
    for (int k = tid; k < TILE; k += blockDim.x) h[k] = 0u;
    __syncthreads();
    const int ne = min(gcur_d[t], CAPT);
    const unsigned int* p = ebuf + (size_t)t * CAPT;
    const uint2* p2 = reinterpret_cast<const uint2*>(p);
    const int ne2 = ne >> 1;
    for (int j = tid; j < ne2; j += blockDim.x) {
        uint2 e2 = p2[j];
        atomicAdd(&h[e2.x >> 23], 1u);
        atomicAdd(&h[e2.y >> 23], 1u);
    }
    if (tid == 0 && (ne & 1)) atomicAdd(&h[p[ne - 1] >> 23], 1u);
    __syncthreads();
    int v0 = (int)h[2 * tid];
    int v1 = (int)h[2 * tid + 1];
    int v0p = (v0 + 1) & ~1;
    int v1p = (v1 + 1) & ~1;
    int pair = v0p + v1p;
    stmp[tid] = pair;
    __syncthreads();
    for (int o = 1; o < 256; o <<= 1) {
        int x = (tid >= o) ? stmp[tid - o] : 0;
        __syncthreads();
        stmp[tid] += x;
        __syncthreads();
    }
    int excl = stmp[tid] - pair;             // even
    off[2 * tid] = excl;
    off[2 * tid + 1] = excl + v0p;
    const int base = t << TILE_B;
    {
        int n0 = base + 2 * tid;
        if (n0 < n_nodes)
            nodeinfo[n0].x = ((unsigned int)min(excl, CAPT - 1) << 13) |
                             (unsigned int)min(v0, CAPT - 1);
        int n1 = n0 + 1;
        if (n1 < n_nodes)
            nodeinfo[n1].x = ((unsigned int)min(excl + v0p, CAPT - 1) << 13) |
                             (unsigned int)min(v1, CAPT - 1);
    }
    __syncthreads();
    for (int k = tid; k < TILE; k += blockDim.x) h[k] = (unsigned int)off[k];
    __syncthreads();
    int* sout = sorted_src + (size_t)t * CAPT;
    for (int j = tid; j < ne2; j += blockDim.x) {
        uint2 e2 = p2[j];
        int dlo = (int)(e2.x >> 23);
        int pos = (int)atomicAdd(&h[dlo], 1u);
        if (pos < CAPT) sout[pos] = (int)(e2.x & 0x7fffffu);
        dlo = (int)(e2.y >> 23);
        pos = (int)atomicAdd(&h[dlo], 1u);
        if (pos < CAPT) sout[pos] = (int)(e2.y & 0x7fffffu);
    }
    if (tid == 0 && (ne & 1)) {
        unsigned int e = p[ne - 1];
        int dlo = (int)(e >> 23);
        int pos = (int)atomicAdd(&h[dlo], 1u);
        if (pos < CAPT) sout[pos] = (int)(e & 0x7fffffu);
    }
    __syncthreads();
    // sentinel-fill odd-count holes: h[k] is now the end cursor (off + count)
    for (int k = tid; k < TILE; k += blockDim.x) {
        int endc = (int)h[k];
        int cnt = endc - off[k];
        if ((cnt & 1) && endc < CAPT)
            sout[endc] = n_nodes;    // zero row
    }
}

// ---------- aggregate: wave per node, CSR, bf16 table, branchless int2 pairs ----------
__global__ void aggregate_csr_kernel(const unsigned short* __restrict__ table,
                                     const int* __restrict__ sorted_src,
                                     const uint2* __restrict__ nodeinfo,
                                     float* __restrict__ out, int n_nodes) {
    int gid = blockIdx.x * blockDim.x + threadIdx.x;
    int node = gid >> 6;
    if (node >= n_nodes) return;
    int lane = threadIdx.x & 63;
    int g = lane >> 3;
    int c = lane & 7;
    uint2 ni = nodeinfo[node];                                // single 8B load
    float sn = __uint_as_float(ni.y);
    int start = ((node >> TILE_B) * CAPT) + (int)(ni.x >> 13);  // even
    int cntp = ((int)(ni.x & 0x1fffu) + 1) & ~1;                // padded to even
    float a0 = 0.f, a1 = 0.f, a2 = 0.f, a3 = 0.f, a4 = 0.f, a5 = 0.f, a6 = 0.f, a7 = 0.f;
    for (int k2 = 2 * g; k2 < cntp; k2 += 16) {
        int2 ss = *reinterpret_cast<const int2*>(sorted_src + start + k2);  // 8B aligned
        u32x4 r1 = *reinterpret_cast<const u32x4*>(table + (size_t)ss.x * DIM + c * 8);
        u32x4 r2 = *reinterpret_cast<const u32x4*>(table + (size_t)ss.y * DIM + c * 8);
        a0 += __uint_as_float(r1.x << 16);         a0 += __uint_as_float(r2.x << 16);
        a1 += __uint_as_float(r1.x & 0xffff0000u); a1 += __uint_as_float(r2.x & 0xffff0000u);
        a2 += __uint_as_float(r1.y << 16);         a2 += __uint_as_float(r2.y << 16);
        a3 += __uint_as_float(r1.y & 0xffff0000u); a3 += __uint_as_float(r2.y & 0xffff0000u);
        a4 += __uint_as_float(r1.z << 16);         a4 += __uint_as_float(r2.z << 16);
        a5 += __uint_as_float(r1.z & 0xffff0000u); a5 += __uint_as_float(r2.z & 0xffff0000u);
        a6 += __uint_as_float(r1.w << 16);         a6 += __uint_as_float(r2.w << 16);
        a7 += __uint_as_float(r1.w & 0xffff0000u); a7 += __uint_as_float(r2.w & 0xffff0000u);
    }
    #pragma unroll
    for (int mm = 8; mm <= 32; mm <<= 1) {
        a0 += __shfl_xor(a0, mm, 64); a1 += __shfl_xor(a1, mm, 64);
        a2 += __shfl_xor(a2, mm, 64); a3 += __shfl_xor(a3, mm, 64);
        a4 += __shfl_xor(a4, mm, 64); a5 += __shfl_xor(a5, mm, 64);
        a6 += __shfl_xor(a6, mm, 64); a7 += __shfl_xor(a7, mm, 64);
    }
    if (g == 0) {
        float* o = out + (size_t)node * DIM + c * 8;
        float4 r0 = {a0 * sn, a1 * sn, a2 * sn, a3 * sn};
        float4 r1 = {a4 * sn, a5 * sn, a6 * sn, a7 * sn};
        *reinterpret_cast<float4*>(o) = r0;
        *reinterpret_cast<float4*>(o + 4) = r1;
    }
}

// ---------- fallback path (tiny ws or huge n_nodes) ----------
__global__ void sdeg_atomic_kernel(const int* __restrict__ src, int* __restrict__ sdeg,
                                   int n_edges) {
    int i = blockIdx.x * blockDim.x + threadIdx.x;
    if (i < n_edges) atomicAdd(&sdeg[src[i]], 1);
}
__global__ void sq_from_sdeg_kernel(const int* __restrict__ sdeg, float* __restrict__ sq, int n) {
    int i = blockIdx.x * blockDim.x + threadIdx.x;
    if (i < n) sq[i] = rsqrtf((float)sdeg[i]);
}
__global__ void build_ll_kernel(const int* __restrict__ src, const int* __restrict__ dst,
                                int* __restrict__ head, int2* __restrict__ list, int n_edges) {
    int i = blockIdx.x * blockDim.x + threadIdx.x;
    if (i >= n_edges) return;
    int s = src[i];
    int d = dst[i];
    int prev = atomicExch(&head[d], i);
    list[i] = make_int2(prev, s);
}
__global__ void aggregate_ll_f32_kernel(const float* __restrict__ embed,
                                        const float* __restrict__ sq,
                                        const int* __restrict__ head,
                                        const int2* __restrict__ list,
                                        float* __restrict__ out, int n_nodes) {
    int gid = blockIdx.x * blockDim.x + threadIdx.x;
    int node = gid >> 3;
    if (node >= n_nodes) return;
    int c = gid & 7;
    int cur = head[node];
    float4 A0 = {0.f, 0.f, 0.f, 0.f}, A1 = {0.f, 0.f, 0.f, 0.f};
    while (cur >= 0) {
        int2 v = list[cur];
        cur = v.x;
        int s = v.y;
        float sc = sq[s];
        const float4* row = reinterpret_cast<const float4*>(embed + (size_t)s * DIM + c * 8);
        float4 v0 = row[0], v1 = row[1];
        A0.x += v0.x * sc; A0.y += v0.y * sc; A0.z += v0.z * sc; A0.w += v0.w * sc;
        A1.x += v1.x * sc; A1.y += v1.y * sc; A1.z += v1.z * sc; A1.w += v1.w * sc;
    }
    float sn = sq[node];
    float4 r0 = {A0.x * sn, A0.y * sn, A0.z * sn, A0.w * sn};
    float4 r1 = {A1.x * sn, A1.y * sn, A1.z * sn, A1.w * sn};
    float4* o = reinterpret_cast<float4*>(out + (size_t)node * DIM + c * 8);
    o[0] = r0; o[1] = r1;
}

static inline size_t align16(size_t x) { return (x + 15) & ~(size_t)15; }

extern "C" void kernel_launch(void* const* d_in, const int* in_sizes, int n_in,
                              void* d_out, int out_size, void* d_ws, size_t ws_size,
                              hipStream_t stream) {
    const float* embed = (const float*)d_in[0];
    const int*   src   = (const int*)d_in[1];
    const int*   dst   = (const int*)d_in[2];
    float*       out   = (float*)d_out;

    const int n_nodes = in_sizes[0] / DIM;
    const int n_edges = in_sizes[1];
    const int nt = (n_nodes + TILE - 1) >> TILE_B;
    const int tb = 256;

    // Regions: gcur_d | gcur_s | nodeinfo uint2[n] | ebuf u32 | table bf16[(n+1)*DIM]
    //          | sbuf u16 | sorted i32
    size_t o_gcur_d = 0;
    size_t o_gcur_s = o_gcur_d + (size_t)MAXNT * 4;
    size_t o_ninfo  = align16(o_gcur_s + (size_t)MAXNT * 4);
    size_t o_ebuf   = align16(o_ninfo + (size_t)n_nodes * 8);
    size_t o_table  = align16(o_ebuf + (size_t)nt * CAPT * 4);
    size_t o_sbuf   = align16(o_table + (size_t)(n_nodes + 1) * DIM * 2);
    size_t o_sorted = align16(o_sbuf + (size_t)nt * CAPT * 2);
    size_t need     = o_sorted + (size_t)nt * CAPT * 4;

    const bool fast = (nt <= MAXNT) && (n_nodes <= (1 << 23)) && (ws_size >= need);

    if (fast) {
        char* ws = (char*)d_ws;
        int* gcur_d = (int*)(ws + o_gcur_d);
        int* gcur_s = (int*)(ws + o_gcur_s);
        uint2* nodeinfo = (uint2*)(ws + o_ninfo);
        unsigned int*   ebuf  = (unsigned int*)(ws + o_ebuf);
        unsigned short* table = (unsigned short*)(ws + o_table);
        unsigned short* sbuf  = (unsigned short*)(ws + o_sbuf);
        int* sorted_src = (int*)(ws + o_sorted);

        unsigned int* pad_row = (unsigned int*)(table + (size_t)n_nodes * DIM);
        zero_init_kernel<<<5, 256, 0, stream>>>(gcur_d, pad_row);

        const int g1 = (n_edges + CHUNK - 1) / CHUNK;
        partition_kernel<<<g1, tb, 0, stream>>>(src, dst, gcur_d, gcur_s, ebuf, sbuf,
                                                n_edges, nt);
        tile_build_kernel<<<2 * nt, tb, 0, stream>>>(ebuf, sbuf, gcur_d, gcur_s, embed,
                                                     sorted_src, nodeinfo, table,
                                                     n_nodes, nt);
        const long long at = (long long)n_nodes * 64;
        aggregate_csr_kernel<<<(int)((at + 127) / 128), 128, 0, stream>>>(
            table, sorted_src, nodeinfo, out, n_nodes);
    } else {
        int*   head = (int*)d_ws;
        float* sq   = (float*)(head + n_nodes);
        int*   sdeg = (int*)(sq + n_nodes);
        int2*  list = (int2*)(sdeg + n_nodes);
        (void)hipMemsetAsync(head, 0xFF, (size_t)n_nodes * 4, stream);
        (void)hipMemsetAsync(sdeg, 0, (size_t)n_nodes * 4, stream);
        sdeg_atomic_kernel<<<(n_edges + tb - 1) / tb, tb, 0, stream>>>(src, sdeg, n_edges);
        sq_from_sdeg_kernel<<<(n_nodes + tb - 1) / tb, tb, 0, stream>>>(sdeg, sq, n_nodes);
        build_ll_kernel<<<(n_edges + tb - 1) / tb, tb, 0, stream>>>(src, dst, head,
                                                                    list, n_edges);
        const int at = n_nodes * 8;
        aggregate_ll_f32_kernel<<<(at + tb - 1) / tb, tb, 0, stream>>>(
            embed, sq, head, list, out, n_nodes);
    }
}